// Round 3
// baseline (292.181 us; speedup 1.0000x reference)
//
#include <hip/hip_runtime.h>

#define N_   64
#define C_   2048
#define HW_  288
#define P_   5
#define CM_  3328   // C_ + P_*256
#define LOC_ 1280   // P_*256
#define SEGC 8      // K segments for loc GEMM  (2048/256)
#define SEGM 13     // K segments for merge GEMM (3328/256)

#define WPITCH 72   // GEMM LDS tile pitch (bf16): 36 dwords -> <=2-way (free)

typedef __attribute__((ext_vector_type(8))) short bf16x8;
typedef __attribute__((ext_vector_type(4))) float f32x4;

__device__ __forceinline__ unsigned short f2bf(float f) {   // fp32 -> bf16 RNE
  unsigned u = __float_as_uint(f);
  u = (u + 0x7FFFu + ((u >> 16) & 1u)) >> 16;
  return (unsigned short)u;
}
__device__ __forceinline__ unsigned pack2(float lo, float hi) {
  return (unsigned)f2bf(lo) | ((unsigned)f2bf(hi) << 16);
}

// direct global->LDS 16B (no VGPR round-trip). dst must be wave-uniform base.
__device__ __forceinline__ void load16_lds(const float4* g, void* l) {
  __builtin_amdgcn_global_load_lds(
      (const __attribute__((address_space(1))) void*)g,
      (__attribute__((address_space(3))) void*)l, 16, 0, 0);
}

// ---------- Kernel B: one THREAD per channel; x staged via double-buffered LDS
// using global_load_lds width=16 (pre-swizzled per-lane global addresses, linear
// LDS dest). 8 chunks x 144B/channel. Outputs avgB (bf16) + gfeat region of catB.
__global__ __launch_bounds__(256) void kB(const float* __restrict__ x,
    const float* __restrict__ poses,
    unsigned short* __restrict__ avgB, unsigned short* __restrict__ catB) {
  __shared__ float lds[2][256 * 36];                 // 2 x 36864 B
  const int t  = threadIdx.x;
  const int n  = blockIdx.x >> 3;
  const int cb = (blockIdx.x & 7) << 8;              // channel base
  const int chbase = n * C_ + cb;

  // box -> bitmask (exact reference op order, fp32; rintf == np.round)
  unsigned MH[P_], MW[P_];
  float INV[P_];
  const float* kpn = poses + (size_t)n * 68;
#pragma unroll
  for (int p = 0; p < P_; ++p) {
    const float* kp = kpn + 16 * p;
    float px = kp[0], py = kp[1], z = kp[2];
    float bx = fminf(fmaxf(px - 0.25f, 0.f), 0.75f) * z;
    float by = fminf(fmaxf(py - 0.25f, 0.f), 0.75f) * z;
    float bw = 0.5f * z;
    float bh = 0.5f * z;
    int xs = (int)fmaxf(0.f,  rintf(12.f * bx));
    int xe = (int)fminf(11.f, rintf(12.f * (bx + bw)));
    int ys = (int)fmaxf(0.f,  rintf(24.f * by));
    int ye = (int)fminf(23.f, rintf(24.f * (by + bh)));
    MH[p] = ((1u << ye) - 1u) & ~((1u << ys) - 1u);
    MW[p] = ((1u << xe) - 1u) & ~((1u << xs) - 1u);
    int area = (ye - ys) * (xe - xs);
    INV[p] = area > 0 ? 1.f / (float)area : 1.f;
  }

  const float4* x4 = (const float4*)x;
  // slot k*256+t -> channel slot/9, word slot%9; LDS byte = slot*16 (linear).
  unsigned goff[9];
#pragma unroll
  for (int k = 0; k < 9; ++k) {
    unsigned slot = k * 256u + (unsigned)t;
    unsigned ch = slot / 9u;
    unsigned j  = slot - 9u * ch;
    goff[k] = (unsigned)(chbase + ch) * 72u + j;     // float4 index; +9 per chunk
  }
  const unsigned wbase = ((unsigned)t & 192u) * 16u; // wave-uniform byte base

  float s[P_] = {0.f, 0.f, 0.f, 0.f, 0.f};
  float mx = -3.402823466e+38f;

  // prologue: stage chunk 0
  {
    char* base = (char*)&lds[0][0];
#pragma unroll
    for (int k = 0; k < 9; ++k)
      load16_lds(x4 + goff[k], base + (k * 4096u + wbase));
  }
  asm volatile("s_waitcnt vmcnt(0)" ::: "memory");
  __syncthreads();

  for (int ci = 0; ci < 8; ++ci) {
    if (ci + 1 < 8) {                                // issue next-chunk DMA early
      char* base = (char*)&lds[(ci + 1) & 1][0];
#pragma unroll
      for (int k = 0; k < 9; ++k)
        load16_lds(x4 + goff[k] + (ci + 1) * 9, base + (k * 4096u + wbase));
    }
    const float* row = &lds[ci & 1][t * 36];
#pragma unroll
    for (int r = 0; r < 3; ++r) {
      int h = 3 * ci + r;
      float4 a = *(const float4*)(row + r * 12 + 0);
      float4 b = *(const float4*)(row + r * 12 + 4);
      float4 c = *(const float4*)(row + r * 12 + 8);
      float m1 = fmaxf(fmaxf(a.x, a.y), fmaxf(a.z, a.w));
      float m2 = fmaxf(fmaxf(b.x, b.y), fmaxf(b.z, b.w));
      float m3 = fmaxf(fmaxf(c.x, c.y), fmaxf(c.z, c.w));
      mx = fmaxf(mx, fmaxf(m1, fmaxf(m2, m3)));
#pragma unroll
      for (int p = 0; p < P_; ++p) {
        unsigned cm = ((MH[p] >> h) & 1u) ? MW[p] : 0u;   // wave-uniform
        if (cm) {
          float t0 = ((cm & 0x001u) ? a.x : 0.f) + ((cm & 0x002u) ? a.y : 0.f);
          float t1 = ((cm & 0x004u) ? a.z : 0.f) + ((cm & 0x008u) ? a.w : 0.f);
          float t2 = ((cm & 0x010u) ? b.x : 0.f) + ((cm & 0x020u) ? b.y : 0.f);
          float t3 = ((cm & 0x040u) ? b.z : 0.f) + ((cm & 0x080u) ? b.w : 0.f);
          float t4 = ((cm & 0x100u) ? c.x : 0.f) + ((cm & 0x200u) ? c.y : 0.f);
          float t5 = ((cm & 0x400u) ? c.z : 0.f) + ((cm & 0x800u) ? c.w : 0.f);
          s[p] += ((t0 + t1) + (t2 + t3)) + (t4 + t5);
        }
      }
    }
    if (ci + 1 < 8) {
      asm volatile("s_waitcnt vmcnt(0)" ::: "memory");  // next chunk landed
      __syncthreads();
    }
  }

  int c = cb + t;
  catB[(size_t)n * CM_ + LOC_ + c] = f2bf(mx);
#pragma unroll
  for (int p = 0; p < P_; ++p)
    avgB[((size_t)n * 5 + p) * C_ + c] = f2bf(s[p] * INV[p]);
}

// ---------- MFMA 64x64 tile over one 256-wide K segment.
// A (bf16, staged as-is), W (fp32, converted to bf16 during staging).
// Depth-2 register prefetch: chunk g+2's loads are issued at phase g, so ~2
// phases (~600-800cy) hide the ~900cy HBM/L2 latency (kC/kD are grid-limited,
// ~1.6 blocks/CU, so TLP alone can't hide it).
template<int NG>
__device__ __forceinline__ void mfma_seg(const uint4* __restrict__ aRow,
                                         const float4* __restrict__ wRow,
                                         unsigned short* As, unsigned short* Ws,
                                         f32x4 acc[4]) {
  const int t  = threadIdx.x;
  const int kq = t & 3;
  const int row = t >> 2;
  const int w  = t >> 6;
  const int l  = t & 63;
  unsigned short* aw = &As[row * WPITCH + kq * 16];
  unsigned short* ww = &Ws[row * WPITCH + kq * 16];
  const int arow16 = (16 * w + (l & 15)) * WPITCH + (l >> 4) * 8;
  const int brow16 = (l & 15) * WPITCH + (l >> 4) * 8;
  uint4 pa[2][2];                    // static-indexed after full unroll (g const)
  float4 pw[2][4];
  pa[0][0] = aRow[0]; pa[0][1] = aRow[1];
  pw[0][0] = wRow[0]; pw[0][1] = wRow[1]; pw[0][2] = wRow[2]; pw[0][3] = wRow[3];
  if (NG > 1) {
    pa[1][0] = aRow[8];  pa[1][1] = aRow[9];
    pw[1][0] = wRow[16]; pw[1][1] = wRow[17];
    pw[1][2] = wRow[18]; pw[1][3] = wRow[19];
  }
#pragma unroll
  for (int g = 0; g < NG; ++g) {
    const int sl = g & 1;
    uint4 pw0, pw1;
    pw0.x = pack2(pw[sl][0].x, pw[sl][0].y); pw0.y = pack2(pw[sl][0].z, pw[sl][0].w);
    pw0.z = pack2(pw[sl][1].x, pw[sl][1].y); pw0.w = pack2(pw[sl][1].z, pw[sl][1].w);
    pw1.x = pack2(pw[sl][2].x, pw[sl][2].y); pw1.y = pack2(pw[sl][2].z, pw[sl][2].w);
    pw1.z = pack2(pw[sl][3].x, pw[sl][3].y); pw1.w = pack2(pw[sl][3].z, pw[sl][3].w);
    uint4 a0 = pa[sl][0], a1 = pa[sl][1];
    if (g) __syncthreads();                       // prev mfma reads done
    *(uint4*)aw = a0; *(uint4*)(aw + 8) = a1;
    *(uint4*)ww = pw0; *(uint4*)(ww + 8) = pw1;
    if (g + 2 < NG) {                             // refill this set: chunk g+2
      pa[sl][0] = aRow[(g + 2) * 8];      pa[sl][1] = aRow[(g + 2) * 8 + 1];
      pw[sl][0] = wRow[(g + 2) * 16];     pw[sl][1] = wRow[(g + 2) * 16 + 1];
      pw[sl][2] = wRow[(g + 2) * 16 + 2]; pw[sl][3] = wRow[(g + 2) * 16 + 3];
    }
    __syncthreads();
#pragma unroll
    for (int s = 0; s < 2; ++s) {
      bf16x8 af = *(const bf16x8*)&As[arow16 + s * 32];
#pragma unroll
      for (int jm = 0; jm < 4; ++jm) {
        bf16x8 bf = *(const bf16x8*)&Ws[jm * 16 * WPITCH + brow16 + s * 32];
        acc[jm] = __builtin_amdgcn_mfma_f32_16x16x32_bf16(af, bf, acc[jm], 0, 0, 0);
      }
    }
  }
}

// loc GEMM partials: avgB(bf16) x local_w[p]^T -> locP[seg][64][1280] (f32)
__global__ __launch_bounds__(256) void kC(const unsigned short* __restrict__ avgB,
                                          const float* __restrict__ local_w,
                                          float* __restrict__ locP) {
  __shared__ unsigned short As[64 * WPITCH];
  __shared__ unsigned short Ws[64 * WPITCH];
  int b  = blockIdx.x;            // 160 = 5p * 4kt * 8sg
  int p  = b >> 5;
  int kt = (b >> 3) & 3;
  int sg = b & 7;
  const int t = threadIdx.x, row = t >> 2, kq = t & 3, w = t >> 6, l = t & 63;
  const uint4*  aRow = (const uint4*)avgB + ((size_t)row * 5 + p) * 256 + sg * 32 + kq * 2;
  const float4* wRow = (const float4*)(local_w + ((size_t)p * 256 + kt * 64 + row) * C_
                                       + sg * 256 + kq * 16);
  f32x4 acc[4] = {{0,0,0,0},{0,0,0,0},{0,0,0,0},{0,0,0,0}};
  mfma_seg<4>(aRow, wRow, As, Ws, acc);
  float* outp = locP + (size_t)sg * (N_ * LOC_);
#pragma unroll
  for (int jm = 0; jm < 4; ++jm)
#pragma unroll
    for (int r = 0; r < 4; ++r)
      outp[(size_t)(16 * w + (l >> 4) * 4 + r) * LOC_ + p * 256 + kt * 64 + jm * 16 + (l & 15)]
        = acc[jm][r];
}

// reduce locP over segs + BN + ReLU -> catB[:, 0:1280] (bf16)
__global__ __launch_bounds__(256) void kC2(const float* __restrict__ locP,
    const float* __restrict__ lb, const float* __restrict__ lg, const float* __restrict__ lbe,
    const float* __restrict__ lm, const float* __restrict__ lv,
    unsigned short* __restrict__ catB) {
  int i = blockIdx.x * 256 + threadIdx.x;   // < 64*1280
  int n = i / LOC_;
  int q = i - n * LOC_;
  float s = 0.f;
#pragma unroll
  for (int sg = 0; sg < SEGC; ++sg) s += locP[(size_t)sg * (N_ * LOC_) + i];
  float sc = lg[q] / sqrtf(lv[q] + 1e-5f);
  float v = (s + lb[q] - lm[q]) * sc + lbe[q];
  catB[(size_t)n * CM_ + q] = f2bf(fmaxf(v, 0.f));
}

// merge GEMM partials: catB(bf16) x merge_w^T -> mrgP[seg][64][2048] (f32).
// Block 0 also zeroes kE's spin flags (any kD write is visible before kE starts).
__global__ __launch_bounds__(256) void kD(const unsigned short* __restrict__ catB,
                                          const float* __restrict__ merge_w,
                                          float* __restrict__ mrgP,
                                          unsigned* __restrict__ flags) {
  __shared__ unsigned short As[64 * WPITCH];
  __shared__ unsigned short Ws[64 * WPITCH];
  if (blockIdx.x == 0 && threadIdx.x < 256) flags[threadIdx.x] = 0u;
  int b  = blockIdx.x;            // 416 = 32 jt * 13 sg
  int jt = b / SEGM;
  int sg = b - jt * SEGM;
  const int t = threadIdx.x, row = t >> 2, kq = t & 3, w = t >> 6, l = t & 63;
  const uint4*  aRow = (const uint4*)catB + (size_t)row * 416 + sg * 32 + kq * 2;
  const float4* wRow = (const float4*)(merge_w + (size_t)(jt * 64 + row) * CM_
                                       + sg * 256 + kq * 16);
  f32x4 acc[4] = {{0,0,0,0},{0,0,0,0},{0,0,0,0},{0,0,0,0}};
  mfma_seg<4>(aRow, wRow, As, Ws, acc);
  float* outp = mrgP + (size_t)sg * (N_ * C_);
#pragma unroll
  for (int jm = 0; jm < 4; ++jm)
#pragma unroll
    for (int r = 0; r < 4; ++r)
      outp[(size_t)(16 * w + (l >> 4) * 4 + r) * C_ + jt * 64 + jm * 16 + (l & 15)]
        = acc[jm][r];
}

// kE: fused {reduce mrgP over segs + BN + ReLU + L2-normalize}. 256 blocks x
// 128 threads (all co-resident: 512 waves << 2048-wave capacity), float4 per
// thread. Cross-block sumsq exchange via deterministic flag/spin (4 sibling
// blocks per row, fixed summation order). z never touches memory.
__global__ __launch_bounds__(128) void kE(const float* __restrict__ mrgP,
    const float* __restrict__ mb, const float* __restrict__ mg,
    const float* __restrict__ mbe, const float* __restrict__ mm,
    const float* __restrict__ mv, float* __restrict__ out,
    float* __restrict__ part, unsigned* __restrict__ flags) {
  const int b = blockIdx.x;                 // n*4 + jb
  const int n = b >> 2, t = threadIdx.x;
  const int j = ((b & 3) << 9) + (t << 2);  // 4 channels per thread
  float4 y = {0.f, 0.f, 0.f, 0.f};
#pragma unroll
  for (int sg = 0; sg < SEGM; ++sg) {
    float4 v = *(const float4*)&mrgP[(size_t)sg * (N_ * C_) + (size_t)n * C_ + j];
    y.x += v.x; y.y += v.y; y.z += v.z; y.w += v.w;
  }
  float4 G  = *(const float4*)&mg[j];
  float4 V  = *(const float4*)&mv[j];
  float4 B  = *(const float4*)&mb[j];
  float4 M  = *(const float4*)&mm[j];
  float4 Be = *(const float4*)&mbe[j];
  float z0 = fmaxf((y.x + B.x - M.x) * (G.x / sqrtf(V.x + 1e-5f)) + Be.x, 0.f);
  float z1 = fmaxf((y.y + B.y - M.y) * (G.y / sqrtf(V.y + 1e-5f)) + Be.y, 0.f);
  float z2 = fmaxf((y.z + B.z - M.z) * (G.z / sqrtf(V.z + 1e-5f)) + Be.z, 0.f);
  float z3 = fmaxf((y.w + B.w - M.w) * (G.w / sqrtf(V.w + 1e-5f)) + Be.w, 0.f);
  float ss = (z0 * z0 + z1 * z1) + (z2 * z2 + z3 * z3);
#pragma unroll
  for (int off = 32; off; off >>= 1) ss += __shfl_xor(ss, off, 64);
  __shared__ float red[2];
  __shared__ float tots;
  if ((t & 63) == 0) red[t >> 6] = ss;
  __syncthreads();
  if (t == 0) {
    part[b] = red[0] + red[1];
    __hip_atomic_store(&flags[b], 1u, __ATOMIC_RELEASE, __HIP_MEMORY_SCOPE_AGENT);
    const int base = b & ~3;
    float tot = 0.f;
#pragma unroll
    for (int k = 0; k < 4; ++k) {
      while (__hip_atomic_load(&flags[base + k], __ATOMIC_ACQUIRE,
                               __HIP_MEMORY_SCOPE_AGENT) == 0u) {}
      tot += __hip_atomic_load(&part[base + k], __ATOMIC_RELAXED,
                               __HIP_MEMORY_SCOPE_AGENT);
    }
    tots = tot;
  }
  __syncthreads();
  float inv = 1.f / fmaxf(sqrtf(tots), 1e-12f);
  float4 o;
  o.x = z0 * inv; o.y = z1 * inv; o.z = z2 * inv; o.w = z3 * inv;
  *(float4*)&out[(size_t)n * C_ + j] = o;
}

extern "C" void kernel_launch(void* const* d_in, const int* in_sizes, int n_in,
                              void* d_out, int out_size, void* d_ws, size_t ws_size,
                              hipStream_t stream) {
  const float* x          = (const float*)d_in[0];
  const float* poses      = (const float*)d_in[1];
  const float* local_w    = (const float*)d_in[2];
  const float* local_b    = (const float*)d_in[3];
  const float* local_g    = (const float*)d_in[4];
  const float* local_be   = (const float*)d_in[5];
  const float* local_m    = (const float*)d_in[6];
  const float* local_v    = (const float*)d_in[7];
  const float* merge_w    = (const float*)d_in[8];
  const float* merge_b    = (const float*)d_in[9];
  const float* merge_g    = (const float*)d_in[10];
  const float* merge_be   = (const float*)d_in[11];
  const float* merge_m    = (const float*)d_in[12];
  const float* merge_v    = (const float*)d_in[13];

  char* ws = (char*)d_ws;
  unsigned short* catB = (unsigned short*)ws;                 // 64*3328 bf16  = 425984 B
  unsigned short* avgB = (unsigned short*)(ws + 425984);      // 64*5*2048 bf16 = 1310720 B
  float* locP = (float*)(ws + 1736704);                       // 8*64*1280 f32  = 2621440 B
  float* mrgP = (float*)(ws + 4358144);                       // 13*64*2048 f32 = 6815744 B
  float*    part  = (float*)(ws + 11173888);                  // 256 f32
  unsigned* flags = (unsigned*)(ws + 11174912);               // 256 u32

  kB<<<512, 256, 0, stream>>>(x, poses, avgB, catB);
  kC<<<20 * SEGC, 256, 0, stream>>>(avgB, local_w, locP);
  kC2<<<(N_ * LOC_) / 256, 256, 0, stream>>>(locP, local_b, local_g, local_be,
                                             local_m, local_v, catB);
  kD<<<32 * SEGM, 256, 0, stream>>>(catB, merge_w, mrgP, flags);
  kE<<<256, 128, 0, stream>>>(mrgP, merge_b, merge_g, merge_be, merge_m, merge_v,
                              (float*)d_out, part, flags);
}

// Round 4
// 282.049 us; speedup vs baseline: 1.0359x; 1.0359x over previous
//
#include <hip/hip_runtime.h>

#define N_   64
#define C_   2048
#define HW_  288
#define P_   5
#define CM_  3328   // C_ + P_*256
#define LOC_ 1280   // P_*256
#define SEGC 8      // K segments for loc GEMM  (2048/256)
#define SEGM 13     // K segments for merge GEMM (3328/256)

#define WPITCH 72   // GEMM LDS tile pitch (bf16): 36 dwords -> <=2-way (free)

typedef __attribute__((ext_vector_type(8))) short bf16x8;
typedef __attribute__((ext_vector_type(4))) float f32x4;

__device__ __forceinline__ unsigned short f2bf(float f) {   // fp32 -> bf16 RNE
  unsigned u = __float_as_uint(f);
  u = (u + 0x7FFFu + ((u >> 16) & 1u)) >> 16;
  return (unsigned short)u;
}
__device__ __forceinline__ unsigned pack2(float lo, float hi) {
  return (unsigned)f2bf(lo) | ((unsigned)f2bf(hi) << 16);
}

// direct global->LDS 16B (no VGPR round-trip). dst must be wave-uniform base.
__device__ __forceinline__ void load16_lds(const float4* g, void* l) {
  __builtin_amdgcn_global_load_lds(
      (const __attribute__((address_space(1))) void*)g,
      (__attribute__((address_space(3))) void*)l, 16, 0, 0);
}

// ---------- Kernel B: one THREAD per channel; x staged via double-buffered LDS
// using global_load_lds width=16 (pre-swizzled per-lane global addresses, linear
// LDS dest). 8 chunks x 144B/channel. Outputs avgB (bf16) + gfeat region of catB.
__global__ __launch_bounds__(256) void kB(const float* __restrict__ x,
    const float* __restrict__ poses,
    unsigned short* __restrict__ avgB, unsigned short* __restrict__ catB) {
  __shared__ float lds[2][256 * 36];                 // 2 x 36864 B
  const int t  = threadIdx.x;
  const int n  = blockIdx.x >> 3;
  const int cb = (blockIdx.x & 7) << 8;              // channel base
  const int chbase = n * C_ + cb;

  // box -> bitmask (exact reference op order, fp32; rintf == np.round)
  unsigned MH[P_], MW[P_];
  float INV[P_];
  const float* kpn = poses + (size_t)n * 68;
#pragma unroll
  for (int p = 0; p < P_; ++p) {
    const float* kp = kpn + 16 * p;
    float px = kp[0], py = kp[1], z = kp[2];
    float bx = fminf(fmaxf(px - 0.25f, 0.f), 0.75f) * z;
    float by = fminf(fmaxf(py - 0.25f, 0.f), 0.75f) * z;
    float bw = 0.5f * z;
    float bh = 0.5f * z;
    int xs = (int)fmaxf(0.f,  rintf(12.f * bx));
    int xe = (int)fminf(11.f, rintf(12.f * (bx + bw)));
    int ys = (int)fmaxf(0.f,  rintf(24.f * by));
    int ye = (int)fminf(23.f, rintf(24.f * (by + bh)));
    MH[p] = ((1u << ye) - 1u) & ~((1u << ys) - 1u);
    MW[p] = ((1u << xe) - 1u) & ~((1u << xs) - 1u);
    int area = (ye - ys) * (xe - xs);
    INV[p] = area > 0 ? 1.f / (float)area : 1.f;
  }

  const float4* x4 = (const float4*)x;
  // slot k*256+t -> channel slot/9, word slot%9; LDS byte = slot*16 (linear).
  unsigned goff[9];
#pragma unroll
  for (int k = 0; k < 9; ++k) {
    unsigned slot = k * 256u + (unsigned)t;
    unsigned ch = slot / 9u;
    unsigned j  = slot - 9u * ch;
    goff[k] = (unsigned)(chbase + ch) * 72u + j;     // float4 index; +9 per chunk
  }
  const unsigned wbase = ((unsigned)t & 192u) * 16u; // wave-uniform byte base

  float s[P_] = {0.f, 0.f, 0.f, 0.f, 0.f};
  float mx = -3.402823466e+38f;

  // prologue: stage chunk 0
  {
    char* base = (char*)&lds[0][0];
#pragma unroll
    for (int k = 0; k < 9; ++k)
      load16_lds(x4 + goff[k], base + (k * 4096u + wbase));
  }
  asm volatile("s_waitcnt vmcnt(0)" ::: "memory");
  __syncthreads();

  for (int ci = 0; ci < 8; ++ci) {
    if (ci + 1 < 8) {                                // issue next-chunk DMA early
      char* base = (char*)&lds[(ci + 1) & 1][0];
#pragma unroll
      for (int k = 0; k < 9; ++k)
        load16_lds(x4 + goff[k] + (ci + 1) * 9, base + (k * 4096u + wbase));
    }
    const float* row = &lds[ci & 1][t * 36];
#pragma unroll
    for (int r = 0; r < 3; ++r) {
      int h = 3 * ci + r;
      float4 a = *(const float4*)(row + r * 12 + 0);
      float4 b = *(const float4*)(row + r * 12 + 4);
      float4 c = *(const float4*)(row + r * 12 + 8);
      float m1 = fmaxf(fmaxf(a.x, a.y), fmaxf(a.z, a.w));
      float m2 = fmaxf(fmaxf(b.x, b.y), fmaxf(b.z, b.w));
      float m3 = fmaxf(fmaxf(c.x, c.y), fmaxf(c.z, c.w));
      mx = fmaxf(mx, fmaxf(m1, fmaxf(m2, m3)));
#pragma unroll
      for (int p = 0; p < P_; ++p) {
        unsigned cm = ((MH[p] >> h) & 1u) ? MW[p] : 0u;   // wave-uniform
        if (cm) {
          float t0 = ((cm & 0x001u) ? a.x : 0.f) + ((cm & 0x002u) ? a.y : 0.f);
          float t1 = ((cm & 0x004u) ? a.z : 0.f) + ((cm & 0x008u) ? a.w : 0.f);
          float t2 = ((cm & 0x010u) ? b.x : 0.f) + ((cm & 0x020u) ? b.y : 0.f);
          float t3 = ((cm & 0x040u) ? b.z : 0.f) + ((cm & 0x080u) ? b.w : 0.f);
          float t4 = ((cm & 0x100u) ? c.x : 0.f) + ((cm & 0x200u) ? c.y : 0.f);
          float t5 = ((cm & 0x400u) ? c.z : 0.f) + ((cm & 0x800u) ? c.w : 0.f);
          s[p] += ((t0 + t1) + (t2 + t3)) + (t4 + t5);
        }
      }
    }
    if (ci + 1 < 8) {
      asm volatile("s_waitcnt vmcnt(0)" ::: "memory");  // next chunk landed
      __syncthreads();
    }
  }

  int c = cb + t;
  catB[(size_t)n * CM_ + LOC_ + c] = f2bf(mx);
#pragma unroll
  for (int p = 0; p < P_; ++p)
    avgB[((size_t)n * 5 + p) * C_ + c] = f2bf(s[p] * INV[p]);
}

// ---------- MFMA 64x64 tile over one 256-wide K segment.
// A (bf16, staged as-is), W (fp32, converted to bf16 during staging).
// Depth-2 register prefetch: chunk g+2's loads are issued at phase g, so ~2
// phases (~600-800cy) hide the ~900cy HBM/L2 latency (kC/kD are grid-limited,
// ~1.6 blocks/CU, so TLP alone can't hide it).
template<int NG>
__device__ __forceinline__ void mfma_seg(const uint4* __restrict__ aRow,
                                         const float4* __restrict__ wRow,
                                         unsigned short* As, unsigned short* Ws,
                                         f32x4 acc[4]) {
  const int t  = threadIdx.x;
  const int kq = t & 3;
  const int row = t >> 2;
  const int w  = t >> 6;
  const int l  = t & 63;
  unsigned short* aw = &As[row * WPITCH + kq * 16];
  unsigned short* ww = &Ws[row * WPITCH + kq * 16];
  const int arow16 = (16 * w + (l & 15)) * WPITCH + (l >> 4) * 8;
  const int brow16 = (l & 15) * WPITCH + (l >> 4) * 8;
  uint4 pa[2][2];                    // static-indexed after full unroll (g const)
  float4 pw[2][4];
  pa[0][0] = aRow[0]; pa[0][1] = aRow[1];
  pw[0][0] = wRow[0]; pw[0][1] = wRow[1]; pw[0][2] = wRow[2]; pw[0][3] = wRow[3];
  if (NG > 1) {
    pa[1][0] = aRow[8];  pa[1][1] = aRow[9];
    pw[1][0] = wRow[16]; pw[1][1] = wRow[17];
    pw[1][2] = wRow[18]; pw[1][3] = wRow[19];
  }
#pragma unroll
  for (int g = 0; g < NG; ++g) {
    const int sl = g & 1;
    uint4 pw0, pw1;
    pw0.x = pack2(pw[sl][0].x, pw[sl][0].y); pw0.y = pack2(pw[sl][0].z, pw[sl][0].w);
    pw0.z = pack2(pw[sl][1].x, pw[sl][1].y); pw0.w = pack2(pw[sl][1].z, pw[sl][1].w);
    pw1.x = pack2(pw[sl][2].x, pw[sl][2].y); pw1.y = pack2(pw[sl][2].z, pw[sl][2].w);
    pw1.z = pack2(pw[sl][3].x, pw[sl][3].y); pw1.w = pack2(pw[sl][3].z, pw[sl][3].w);
    uint4 a0 = pa[sl][0], a1 = pa[sl][1];
    if (g) __syncthreads();                       // prev mfma reads done
    *(uint4*)aw = a0; *(uint4*)(aw + 8) = a1;
    *(uint4*)ww = pw0; *(uint4*)(ww + 8) = pw1;
    if (g + 2 < NG) {                             // refill this set: chunk g+2
      pa[sl][0] = aRow[(g + 2) * 8];      pa[sl][1] = aRow[(g + 2) * 8 + 1];
      pw[sl][0] = wRow[(g + 2) * 16];     pw[sl][1] = wRow[(g + 2) * 16 + 1];
      pw[sl][2] = wRow[(g + 2) * 16 + 2]; pw[sl][3] = wRow[(g + 2) * 16 + 3];
    }
    __syncthreads();
#pragma unroll
    for (int s = 0; s < 2; ++s) {
      bf16x8 af = *(const bf16x8*)&As[arow16 + s * 32];
#pragma unroll
      for (int jm = 0; jm < 4; ++jm) {
        bf16x8 bf = *(const bf16x8*)&Ws[jm * 16 * WPITCH + brow16 + s * 32];
        acc[jm] = __builtin_amdgcn_mfma_f32_16x16x32_bf16(af, bf, acc[jm], 0, 0, 0);
      }
    }
  }
}

// loc GEMM partials: avgB(bf16) x local_w[p]^T -> locP[seg][64][1280] (f32)
__global__ __launch_bounds__(256) void kC(const unsigned short* __restrict__ avgB,
                                          const float* __restrict__ local_w,
                                          float* __restrict__ locP) {
  __shared__ unsigned short As[64 * WPITCH];
  __shared__ unsigned short Ws[64 * WPITCH];
  int b  = blockIdx.x;            // 160 = 5p * 4kt * 8sg
  int p  = b >> 5;
  int kt = (b >> 3) & 3;
  int sg = b & 7;
  const int t = threadIdx.x, row = t >> 2, kq = t & 3, w = t >> 6, l = t & 63;
  const uint4*  aRow = (const uint4*)avgB + ((size_t)row * 5 + p) * 256 + sg * 32 + kq * 2;
  const float4* wRow = (const float4*)(local_w + ((size_t)p * 256 + kt * 64 + row) * C_
                                       + sg * 256 + kq * 16);
  f32x4 acc[4] = {{0,0,0,0},{0,0,0,0},{0,0,0,0},{0,0,0,0}};
  mfma_seg<4>(aRow, wRow, As, Ws, acc);
  float* outp = locP + (size_t)sg * (N_ * LOC_);
#pragma unroll
  for (int jm = 0; jm < 4; ++jm)
#pragma unroll
    for (int r = 0; r < 4; ++r)
      outp[(size_t)(16 * w + (l >> 4) * 4 + r) * LOC_ + p * 256 + kt * 64 + jm * 16 + (l & 15)]
        = acc[jm][r];
}

// reduce locP over segs + BN + ReLU -> catB[:, 0:1280] (bf16)
__global__ __launch_bounds__(256) void kC2(const float* __restrict__ locP,
    const float* __restrict__ lb, const float* __restrict__ lg, const float* __restrict__ lbe,
    const float* __restrict__ lm, const float* __restrict__ lv,
    unsigned short* __restrict__ catB) {
  int i = blockIdx.x * 256 + threadIdx.x;   // < 64*1280
  int n = i / LOC_;
  int q = i - n * LOC_;
  float s = 0.f;
#pragma unroll
  for (int sg = 0; sg < SEGC; ++sg) s += locP[(size_t)sg * (N_ * LOC_) + i];
  float sc = lg[q] / sqrtf(lv[q] + 1e-5f);
  float v = (s + lb[q] - lm[q]) * sc + lbe[q];
  catB[(size_t)n * CM_ + q] = f2bf(fmaxf(v, 0.f));
}

// merge GEMM partials: catB(bf16) x merge_w^T -> mrgP[seg][64][2048] (f32)
__global__ __launch_bounds__(256) void kD(const unsigned short* __restrict__ catB,
                                          const float* __restrict__ merge_w,
                                          float* __restrict__ mrgP) {
  __shared__ unsigned short As[64 * WPITCH];
  __shared__ unsigned short Ws[64 * WPITCH];
  int b  = blockIdx.x;            // 416 = 32 jt * 13 sg
  int jt = b / SEGM;
  int sg = b - jt * SEGM;
  const int t = threadIdx.x, row = t >> 2, kq = t & 3, w = t >> 6, l = t & 63;
  const uint4*  aRow = (const uint4*)catB + (size_t)row * 416 + sg * 32 + kq * 2;
  const float4* wRow = (const float4*)(merge_w + (size_t)(jt * 64 + row) * CM_
                                       + sg * 256 + kq * 16);
  f32x4 acc[4] = {{0,0,0,0},{0,0,0,0},{0,0,0,0},{0,0,0,0}};
  mfma_seg<4>(aRow, wRow, As, Ws, acc);
  float* outp = mrgP + (size_t)sg * (N_ * C_);
#pragma unroll
  for (int jm = 0; jm < 4; ++jm)
#pragma unroll
    for (int r = 0; r < 4; ++r)
      outp[(size_t)(16 * w + (l >> 4) * 4 + r) * C_ + jt * 64 + jm * 16 + (l & 15)]
        = acc[jm][r];
}

// kE1: reduce mrgP over segs + BN + ReLU -> z (f32), per-(n,jb) sumsq partials.
// 512 blocks so the 6.8 MB reduction uses the full chip.
__global__ __launch_bounds__(256) void kE1(const float* __restrict__ mrgP,
    const float* __restrict__ mb, const float* __restrict__ mg, const float* __restrict__ mbe,
    const float* __restrict__ mm, const float* __restrict__ mv,
    float* __restrict__ z, float* __restrict__ part) {
  int nb = blockIdx.x;                   // n*8 + jb
  int n = nb >> 3, t = threadIdx.x;
  int j = ((nb & 7) << 8) + t;
  float y = 0.f;
#pragma unroll
  for (int sg = 0; sg < SEGM; ++sg) y += mrgP[(size_t)sg * (N_ * C_) + (size_t)n * C_ + j];
  float sc = mg[j] / sqrtf(mv[j] + 1e-5f);
  float v = (y + mb[j] - mm[j]) * sc + mbe[j];
  v = fmaxf(v, 0.f);
  z[(size_t)n * C_ + j] = v;
  float ss = v * v;
#pragma unroll
  for (int off = 32; off; off >>= 1) ss += __shfl_xor(ss, off, 64);
  __shared__ float red[4];
  if ((t & 63) == 0) red[t >> 6] = ss;
  __syncthreads();
  if (t == 0) part[nb] = (red[0] + red[1]) + (red[2] + red[3]);
}

// kE2: L2-normalize z -> out
__global__ __launch_bounds__(256) void kE2(const float* __restrict__ z,
    const float* __restrict__ part, float* __restrict__ out) {
  int nb = blockIdx.x;
  int n = nb >> 3, t = threadIdx.x;
  int j = ((nb & 7) << 8) + t;
  const float* pp = part + n * 8;
  float tot = ((pp[0] + pp[1]) + (pp[2] + pp[3])) + ((pp[4] + pp[5]) + (pp[6] + pp[7]));
  float inv = 1.f / fmaxf(sqrtf(tot), 1e-12f);
  out[(size_t)n * C_ + j] = z[(size_t)n * C_ + j] * inv;
}

extern "C" void kernel_launch(void* const* d_in, const int* in_sizes, int n_in,
                              void* d_out, int out_size, void* d_ws, size_t ws_size,
                              hipStream_t stream) {
  const float* x          = (const float*)d_in[0];
  const float* poses      = (const float*)d_in[1];
  const float* local_w    = (const float*)d_in[2];
  const float* local_b    = (const float*)d_in[3];
  const float* local_g    = (const float*)d_in[4];
  const float* local_be   = (const float*)d_in[5];
  const float* local_m    = (const float*)d_in[6];
  const float* local_v    = (const float*)d_in[7];
  const float* merge_w    = (const float*)d_in[8];
  const float* merge_b    = (const float*)d_in[9];
  const float* merge_g    = (const float*)d_in[10];
  const float* merge_be   = (const float*)d_in[11];
  const float* merge_m    = (const float*)d_in[12];
  const float* merge_v    = (const float*)d_in[13];

  char* ws = (char*)d_ws;
  unsigned short* catB = (unsigned short*)ws;                 // 64*3328 bf16  = 425984 B
  unsigned short* avgB = (unsigned short*)(ws + 425984);      // 64*5*2048 bf16 = 1310720 B
  float* locP = (float*)(ws + 1736704);                       // 8*64*1280 f32  = 2621440 B
  float* mrgP = (float*)(ws + 4358144);                       // 13*64*2048 f32 = 6815744 B
  // z/part alias locP (dead after kC2; kE1 runs after kD in-stream)
  float* z    = (float*)(ws + 1736704);                       // 64*2048 f32 = 524288 B
  float* part = (float*)(ws + 2260992);                       // 512 f32

  kB<<<512, 256, 0, stream>>>(x, poses, avgB, catB);
  kC<<<20 * SEGC, 256, 0, stream>>>(avgB, local_w, locP);
  kC2<<<(N_ * LOC_) / 256, 256, 0, stream>>>(locP, local_b, local_g, local_be,
                                             local_m, local_v, catB);
  kD<<<32 * SEGM, 256, 0, stream>>>(catB, merge_w, mrgP);
  kE1<<<512, 256, 0, stream>>>(mrgP, merge_b, merge_g, merge_be, merge_m, merge_v,
                               z, part);
  kE2<<<512, 256, 0, stream>>>(z, part, (float*)d_out);
}